// Round 1
// baseline (412.932 us; speedup 1.0000x reference)
//
#include <hip/hip_runtime.h>
#include <hip/hip_bf16.h>
#include <stdint.h>

// Problem constants (B=2, S=4096, F=512, H=8, D=64)
#define NB 2
#define NS 4096
#define NF 512
#define NH 8
#define ND 64
#define NM (NB * NS)  // 8192 rows for all projections

typedef __attribute__((ext_vector_type(8))) short bf16x8;
typedef __attribute__((ext_vector_type(4))) float f32x4;

static __device__ __forceinline__ unsigned short f2bf(float f) {
    union { float f; uint32_t u; } x; x.f = f;
    uint32_t u = x.u;
    u += 0x7FFFu + ((u >> 16) & 1u);  // RNE
    return (unsigned short)(u >> 16);
}

// global -> LDS direct (width 16). LDS dest must be wave-uniform base; HW adds lane*16.
static __device__ __forceinline__ void load_lds16(const void* g, void* l) {
    __builtin_amdgcn_global_load_lds(
        (const __attribute__((address_space(1))) void*)g,
        (__attribute__((address_space(3))) void*)l,
        16, 0, 0);
}

// ---------------------------------------------------------------------------
// fp32 -> bf16 conversion of activations (q,k,v), vectorized
__global__ void convert_act(const float* __restrict__ q, const float* __restrict__ k,
                            const float* __restrict__ v,
                            unsigned short* __restrict__ qb, unsigned short* __restrict__ kb,
                            unsigned short* __restrict__ vb, int n4) {
    int i0 = blockIdx.x * blockDim.x + threadIdx.x;
    int stride = gridDim.x * blockDim.x;
    for (int i = i0; i < n4; i += stride) {
        float4 a = ((const float4*)q)[i];
        float4 b = ((const float4*)k)[i];
        float4 c = ((const float4*)v)[i];
        ushort4 oa, ob, oc;
        oa.x = f2bf(a.x); oa.y = f2bf(a.y); oa.z = f2bf(a.z); oa.w = f2bf(a.w);
        ob.x = f2bf(b.x); ob.y = f2bf(b.y); ob.z = f2bf(b.z); ob.w = f2bf(b.w);
        oc.x = f2bf(c.x); oc.y = f2bf(c.y); oc.z = f2bf(c.z); oc.w = f2bf(c.w);
        ((ushort4*)qb)[i] = oa;
        ((ushort4*)kb)[i] = ob;
        ((ushort4*)vb)[i] = oc;
    }
}

// Transpose + convert the four weight matrices: WT[n][k] = W[k][n], bf16.
__global__ void convert_w(const float* __restrict__ wq, const float* __restrict__ wk,
                          const float* __restrict__ wv, const float* __restrict__ wo,
                          unsigned short* __restrict__ o0, unsigned short* __restrict__ o1,
                          unsigned short* __restrict__ o2, unsigned short* __restrict__ o3) {
    int i0 = blockIdx.x * blockDim.x + threadIdx.x;
    int stride = gridDim.x * blockDim.x;  // 262144 = one weight per grid-stride step
    for (int i = i0; i < 4 * NF * NF; i += stride) {
        int w = i >> 18;
        int off = i & (NF * NF - 1);
        int r = off >> 9;      // k (row of W)
        int c = off & (NF - 1);  // n (col of W) -> coalesced read
        const float* src = (w == 0) ? wq : (w == 1) ? wk : (w == 2) ? wv : wo;
        unsigned short* dst = (w == 0) ? o0 : (w == 1) ? o1 : (w == 2) ? o2 : o3;
        dst[c * NF + r] = f2bf(src[off]);
    }
}

// ---------------------------------------------------------------------------
// Projection GEMM: C[8192,512] = A[8192,512] @ W[512,512] + bias
// A bf16 row-major; WT bf16 (pre-transposed, [n][k]).
// 128x128 tile, BK=64, 4 waves each 64x64 (4x4 frags of 16x16x32).
// MODE: 0=Q (scale 1/8, out [B,H,S,D] bf16), 1=K (same layout), 2=V (out [B,H,D,S] bf16),
//       3=O (out fp32 row-major [8192,512]).
template <int MODE>
__launch_bounds__(256, 2)
__global__ void proj_gemm(const unsigned short* __restrict__ A,
                          const unsigned short* __restrict__ WT,
                          const float* __restrict__ bias,
                          void* __restrict__ Out) {
    __shared__ unsigned short smem[2 * 128 * 64];  // A tile 16KB + B tile 16KB
    unsigned short* As = smem;
    unsigned short* Bs = smem + 128 * 64;

    const int t = threadIdx.x;
    const int wid = t >> 6;
    const int lane = t & 63;
    const int l15 = lane & 15;
    const int lhi = lane >> 4;
    const int m0 = blockIdx.x * 128;
    const int n0 = blockIdx.y * 128;
    const int wm = (wid >> 1) * 64;
    const int wn = (wid & 1) * 64;

    // staging pattern: thread t covers row t/8, 16B chunk (t%8); source col XOR-swizzled
    const int srow = t >> 3;
    const int scol = ((t & 7) * 16) ^ ((srow & 7) << 4);

    const f32x4 zero4 = {0.f, 0.f, 0.f, 0.f};
    f32x4 acc[4][4];
#pragma unroll
    for (int i = 0; i < 4; ++i)
#pragma unroll
        for (int j = 0; j < 4; ++j) acc[i][j] = zero4;

    for (int k0 = 0; k0 < NF; k0 += 64) {
        __syncthreads();
#pragma unroll
        for (int i = 0; i < 4; ++i) {
            const char* sa = (const char*)A + ((size_t)(m0 + i * 32 + srow) * NF + k0) * 2 + scol;
            load_lds16(sa, (char*)As + i * 4096 + wid * 1024);
            const char* sb = (const char*)WT + ((size_t)(n0 + i * 32 + srow) * NF + k0) * 2 + scol;
            load_lds16(sb, (char*)Bs + i * 4096 + wid * 1024);
        }
        asm volatile("s_waitcnt vmcnt(0)" ::: "memory");
        __syncthreads();

#pragma unroll
        for (int ks = 0; ks < 2; ++ks) {
            bf16x8 af[4], bfr[4];
#pragma unroll
            for (int i = 0; i < 4; ++i) {
                int ra = wm + i * 16 + l15;
                int ca = (ks * 64 + lhi * 16) ^ ((ra & 7) << 4);
                af[i] = *(const bf16x8*)((const char*)As + ra * 128 + ca);
                int rb = wn + i * 16 + l15;
                int cb = (ks * 64 + lhi * 16) ^ ((rb & 7) << 4);
                bfr[i] = *(const bf16x8*)((const char*)Bs + rb * 128 + cb);
            }
#pragma unroll
            for (int mi = 0; mi < 4; ++mi)
#pragma unroll
                for (int ni = 0; ni < 4; ++ni)
                    acc[mi][ni] = __builtin_amdgcn_mfma_f32_16x16x32_bf16(af[mi], bfr[ni], acc[mi][ni], 0, 0, 0);
        }
    }

    // epilogue: C/D layout col = lane&15, row = (lane>>4)*4 + reg
#pragma unroll
    for (int ni = 0; ni < 4; ++ni) {
        int col = n0 + wn + ni * 16 + l15;
        float bv = bias[col];
#pragma unroll
        for (int mi = 0; mi < 4; ++mi) {
#pragma unroll
            for (int r = 0; r < 4; ++r) {
                int row = m0 + wm + mi * 16 + lhi * 4 + r;
                float val = acc[mi][ni][r] + bv;
                if constexpr (MODE == 0 || MODE == 1) {
                    if constexpr (MODE == 0) val *= 0.125f;  // fold 1/sqrt(D)
                    int b = row >> 12, s = row & (NS - 1);
                    int h = col >> 6, d = col & (ND - 1);
                    ((unsigned short*)Out)[((size_t)(b * NH + h) * NS + s) * ND + d] = f2bf(val);
                } else if constexpr (MODE == 2) {  // V transposed: [B,H,D,S]
                    int b = row >> 12, s = row & (NS - 1);
                    int h = col >> 6, d = col & (ND - 1);
                    ((unsigned short*)Out)[((size_t)(b * NH + h) * ND + d) * NS + s] = f2bf(val);
                } else {  // fp32 output
                    ((float*)Out)[(size_t)row * NF + col] = val;
                }
            }
        }
    }
}

// ---------------------------------------------------------------------------
// Fused causal flash attention. Block = 4 waves, Q-tile 128 rows (32/wave), KV tile 64.
// Qh [B,H,S,D] (pre-scaled), Kh [B,H,S,D], VT [B,H,D,S]; out concat [B,S,F] bf16.
__launch_bounds__(256, 2)
__global__ void attn_fused(const unsigned short* __restrict__ Qh,
                           const unsigned short* __restrict__ Kh,
                           const unsigned short* __restrict__ VT,
                           unsigned short* __restrict__ Cc) {
    __shared__ unsigned short smem[16384];  // 32 KB: K 8K | VT 8K | P 4x4K
    unsigned short* Ks = smem;
    unsigned short* Vs = smem + 4096;
    unsigned short* Ps = smem + 8192;

    const int t = threadIdx.x;
    const int wid = t >> 6;
    const int lane = t & 63;
    const int l15 = lane & 15;
    const int lhi = lane >> 4;
    const int qt = 31 - blockIdx.x;  // big tiles dispatch first (load balance)
    const int h = blockIdx.y, b = blockIdx.z;
    const int q0 = qt * 128;
    const size_t bh = (size_t)b * NH + h;
    const unsigned short* Qp = Qh + bh * NS * ND;
    const unsigned short* Kp = Kh + bh * NS * ND;
    const unsigned short* Vp = VT + bh * (size_t)ND * NS;

    // Q fragments stay in registers the whole kernel (A-operand: row = lane&15, k = 8*(lane>>4)+j)
    bf16x8 qf[2][2];
#pragma unroll
    for (int mi = 0; mi < 2; ++mi)
#pragma unroll
        for (int ks = 0; ks < 2; ++ks) {
            int row = q0 + wid * 32 + mi * 16 + l15;
            qf[mi][ks] = *(const bf16x8*)(Qp + (size_t)row * ND + ks * 32 + lhi * 8);
        }

    const f32x4 zero4 = {0.f, 0.f, 0.f, 0.f};
    f32x4 po[2][4];
    float ml[2][4], ll[2][4];
#pragma unroll
    for (int mi = 0; mi < 2; ++mi) {
#pragma unroll
        for (int r = 0; r < 4; ++r) { ml[mi][r] = -1e30f; ll[mi][r] = 0.f; }
#pragma unroll
        for (int ni = 0; ni < 4; ++ni) po[mi][ni] = zero4;
    }

    const int srow = t >> 3;
    const int scol = ((t & 7) * 16) ^ ((srow & 7) << 4);
    unsigned short* Pw = Ps + wid * 2048;  // per-wave 4KB P tile [32][64]

    const int nkv = 2 * qt + 2;
    for (int kt = 0; kt < nkv; ++kt) {
        const int kv0 = kt * 64;
        __syncthreads();  // previous tile fully consumed
#pragma unroll
        for (int i = 0; i < 2; ++i) {
            const char* sk = (const char*)(Kp + (size_t)(kv0 + i * 32 + srow) * ND) + scol;
            load_lds16(sk, (char*)Ks + i * 4096 + wid * 1024);
            const char* sv = (const char*)Vp + ((size_t)(i * 32 + srow) * NS + kv0) * 2 + scol;
            load_lds16(sv, (char*)Vs + i * 4096 + wid * 1024);
        }
        asm volatile("s_waitcnt vmcnt(0)" ::: "memory");
        __syncthreads();

        // S = Q @ K^T  (B-operand col = kv row of Ks)
        f32x4 sf[2][4];
#pragma unroll
        for (int mi = 0; mi < 2; ++mi)
#pragma unroll
            for (int ni = 0; ni < 4; ++ni) sf[mi][ni] = zero4;
#pragma unroll
        for (int ks = 0; ks < 2; ++ks) {
            bf16x8 kf[4];
#pragma unroll
            for (int ni = 0; ni < 4; ++ni) {
                int rk = ni * 16 + l15;
                int ck = (ks * 64 + lhi * 16) ^ ((rk & 7) << 4);
                kf[ni] = *(const bf16x8*)((const char*)Ks + rk * 128 + ck);
            }
#pragma unroll
            for (int mi = 0; mi < 2; ++mi)
#pragma unroll
                for (int ni = 0; ni < 4; ++ni)
                    sf[mi][ni] = __builtin_amdgcn_mfma_f32_16x16x32_bf16(qf[mi][ks], kf[ni], sf[mi][ni], 0, 0, 0);
        }

        // causal mask (only tiles that can touch the diagonal for this wave)
        if (kv0 + 63 > q0 + wid * 32) {
#pragma unroll
            for (int mi = 0; mi < 2; ++mi)
#pragma unroll
                for (int ni = 0; ni < 4; ++ni)
#pragma unroll
                    for (int r = 0; r < 4; ++r) {
                        int row = q0 + wid * 32 + mi * 16 + lhi * 4 + r;
                        int col = kv0 + ni * 16 + l15;
                        if (col > row) sf[mi][ni][r] = -1e30f;
                    }
        }

        // online softmax (wave-parallel; rows live in 16-lane groups)
#pragma unroll
        for (int mi = 0; mi < 2; ++mi) {
#pragma unroll
            for (int r = 0; r < 4; ++r) {
                float mx = fmaxf(fmaxf(sf[mi][0][r], sf[mi][1][r]),
                                 fmaxf(sf[mi][2][r], sf[mi][3][r]));
                mx = fmaxf(mx, __shfl_xor(mx, 1));
                mx = fmaxf(mx, __shfl_xor(mx, 2));
                mx = fmaxf(mx, __shfl_xor(mx, 4));
                mx = fmaxf(mx, __shfl_xor(mx, 8));
                float mnew = fmaxf(ml[mi][r], mx);
                float a = __expf(ml[mi][r] - mnew);
                ml[mi][r] = mnew;
                float rs = 0.f;
#pragma unroll
                for (int ni = 0; ni < 4; ++ni) {
                    float p = __expf(sf[mi][ni][r] - mnew);
                    sf[mi][ni][r] = p;
                    rs += p;
                }
                rs += __shfl_xor(rs, 1);
                rs += __shfl_xor(rs, 2);
                rs += __shfl_xor(rs, 4);
                rs += __shfl_xor(rs, 8);
                ll[mi][r] = ll[mi][r] * a + rs;
#pragma unroll
                for (int ni = 0; ni < 4; ++ni) po[mi][ni][r] *= a;
            }
        }

        // P (C-layout) -> per-wave LDS (swizzled) -> A-layout fragments
#pragma unroll
        for (int mi = 0; mi < 2; ++mi)
#pragma unroll
            for (int ni = 0; ni < 4; ++ni)
#pragma unroll
                for (int r = 0; r < 4; ++r) {
                    int row = mi * 16 + lhi * 4 + r;
                    int cb = ((ni * 16 + l15) * 2) ^ ((row & 7) << 4);
                    *(unsigned short*)((char*)Pw + row * 128 + cb) = f2bf(sf[mi][ni][r]);
                }
        asm volatile("s_waitcnt lgkmcnt(0)" ::: "memory");
        __builtin_amdgcn_sched_barrier(0);

        // O += P @ V   (B-operand col = d row of Vs)
#pragma unroll
        for (int ks = 0; ks < 2; ++ks) {
            bf16x8 pf[2], vf[4];
#pragma unroll
            for (int mi = 0; mi < 2; ++mi) {
                int rp = mi * 16 + l15;
                int cp = (ks * 64 + lhi * 16) ^ ((rp & 7) << 4);
                pf[mi] = *(const bf16x8*)((const char*)Pw + rp * 128 + cp);
            }
#pragma unroll
            for (int ni = 0; ni < 4; ++ni) {
                int rv = ni * 16 + l15;
                int cv = (ks * 64 + lhi * 16) ^ ((rv & 7) << 4);
                vf[ni] = *(const bf16x8*)((const char*)Vs + rv * 128 + cv);
            }
#pragma unroll
            for (int mi = 0; mi < 2; ++mi)
#pragma unroll
                for (int ni = 0; ni < 4; ++ni)
                    po[mi][ni] = __builtin_amdgcn_mfma_f32_16x16x32_bf16(pf[mi], vf[ni], po[mi][ni], 0, 0, 0);
        }
    }

    // normalize + store concat [B,S,F]
#pragma unroll
    for (int mi = 0; mi < 2; ++mi)
#pragma unroll
        for (int r = 0; r < 4; ++r) {
            float inv = 1.f / ll[mi][r];
            int row = q0 + wid * 32 + mi * 16 + lhi * 4 + r;
            size_t base = ((size_t)b * NS + row) * NF + h * ND;
#pragma unroll
            for (int ni = 0; ni < 4; ++ni)
                Cc[base + ni * 16 + l15] = f2bf(po[mi][ni][r] * inv);
        }
}

// ---------------------------------------------------------------------------
extern "C" void kernel_launch(void* const* d_in, const int* in_sizes, int n_in,
                              void* d_out, int out_size, void* d_ws, size_t ws_size,
                              hipStream_t stream) {
    const float* q = (const float*)d_in[0];
    const float* k = (const float*)d_in[1];
    const float* v = (const float*)d_in[2];
    // d_in[3] = mask (deterministic causal; applied analytically)
    const float* wq = (const float*)d_in[4];
    const float* bq = (const float*)d_in[5];
    const float* wk = (const float*)d_in[6];
    const float* bk = (const float*)d_in[7];
    const float* wv = (const float*)d_in[8];
    const float* bv = (const float*)d_in[9];
    const float* wo = (const float*)d_in[10];
    const float* bo = (const float*)d_in[11];

    const size_t MB = 1u << 20;
    char* ws = (char*)d_ws;  // total use: 50 MB
    unsigned short* qb  = (unsigned short*)(ws);             // 8MB (reused as concat)
    unsigned short* kb  = (unsigned short*)(ws + 8 * MB);    // 8MB
    unsigned short* vb  = (unsigned short*)(ws + 16 * MB);   // 8MB
    unsigned short* wqT = (unsigned short*)(ws + 24 * MB);
    unsigned short* wkT = (unsigned short*)(ws + 24 * MB + 512 * 1024);
    unsigned short* wvT = (unsigned short*)(ws + 25 * MB);
    unsigned short* woT = (unsigned short*)(ws + 25 * MB + 512 * 1024);
    unsigned short* Qh  = (unsigned short*)(ws + 26 * MB);   // 8MB [B,H,S,D] pre-scaled
    unsigned short* Kh  = (unsigned short*)(ws + 34 * MB);   // 8MB [B,H,S,D]
    unsigned short* VTs = (unsigned short*)(ws + 42 * MB);   // 8MB [B,H,D,S]

    convert_act<<<dim3(2048), dim3(256), 0, stream>>>(q, k, v, qb, kb, vb, (NB * NS * NF) / 4);
    convert_w<<<dim3(1024), dim3(256), 0, stream>>>(wq, wk, wv, wo, wqT, wkT, wvT, woT);

    dim3 pg(NM / 128, NF / 128);
    proj_gemm<0><<<pg, dim3(256), 0, stream>>>(qb, wqT, bq, (void*)Qh);
    proj_gemm<1><<<pg, dim3(256), 0, stream>>>(kb, wkT, bk, (void*)Kh);
    proj_gemm<2><<<pg, dim3(256), 0, stream>>>(vb, wvT, bv, (void*)VTs);

    attn_fused<<<dim3(32, NH, NB), dim3(256), 0, stream>>>(Qh, Kh, VTs, qb /*concat*/);

    proj_gemm<3><<<pg, dim3(256), 0, stream>>>(qb, woT, bo, d_out);
}

// Round 4
// 310.783 us; speedup vs baseline: 1.3287x; 1.3287x over previous
//
#include <hip/hip_runtime.h>
#include <hip/hip_bf16.h>
#include <stdint.h>

// Problem constants (B=2, S=4096, F=512, H=8, D=64)
#define NB 2
#define NS 4096
#define NF 512
#define NH 8
#define ND 64
#define NM (NB * NS)  // 8192 rows for all projections

typedef __attribute__((ext_vector_type(8))) short bf16x8;
typedef __attribute__((ext_vector_type(4))) float f32x4;
typedef __attribute__((ext_vector_type(16))) float f32x16;

static __device__ __forceinline__ unsigned short f2bf(float f) {
    union { float f; uint32_t u; } x; x.f = f;
    uint32_t u = x.u;
    u += 0x7FFFu + ((u >> 16) & 1u);  // RNE
    return (unsigned short)(u >> 16);
}

// global -> LDS direct (width 16). LDS dest is wave-uniform base; HW adds lane*16.
static __device__ __forceinline__ void load_lds16(const void* g, void* l) {
    __builtin_amdgcn_global_load_lds(
        (const __attribute__((address_space(1))) void*)g,
        (__attribute__((address_space(3))) void*)l,
        16, 0, 0);
}

// ---------------------------------------------------------------------------
// fp32 -> bf16 conversion: activations (q,k,v) vectorized + weight transposes.
__global__ void convert_all(const float* __restrict__ q, const float* __restrict__ k,
                            const float* __restrict__ v,
                            unsigned short* __restrict__ qb, unsigned short* __restrict__ kb,
                            unsigned short* __restrict__ vb,
                            const float* __restrict__ wq, const float* __restrict__ wk,
                            const float* __restrict__ wv, const float* __restrict__ wo,
                            unsigned short* __restrict__ o0, unsigned short* __restrict__ o1,
                            unsigned short* __restrict__ o2, unsigned short* __restrict__ o3) {
    int i0 = blockIdx.x * blockDim.x + threadIdx.x;
    int stride = gridDim.x * blockDim.x;
    const int n4 = (NB * NS * NF) / 4;
    for (int i = i0; i < n4; i += stride) {
        float4 a = ((const float4*)q)[i];
        float4 b = ((const float4*)k)[i];
        float4 c = ((const float4*)v)[i];
        ushort4 oa, ob, oc;
        oa.x = f2bf(a.x); oa.y = f2bf(a.y); oa.z = f2bf(a.z); oa.w = f2bf(a.w);
        ob.x = f2bf(b.x); ob.y = f2bf(b.y); ob.z = f2bf(b.z); ob.w = f2bf(b.w);
        oc.x = f2bf(c.x); oc.y = f2bf(c.y); oc.z = f2bf(c.z); oc.w = f2bf(c.w);
        ((ushort4*)qb)[i] = oa;
        ((ushort4*)kb)[i] = ob;
        ((ushort4*)vb)[i] = oc;
    }
    // weights: WT[n][k] = W[k][n]
    for (int i = i0; i < 4 * NF * NF; i += stride) {
        int w = i >> 18;
        int off = i & (NF * NF - 1);
        int r = off >> 9;        // k (row of W)
        int c = off & (NF - 1);  // n (col of W) -> coalesced read
        const float* src = (w == 0) ? wq : (w == 1) ? wk : (w == 2) ? wv : wo;
        unsigned short* dst = (w == 0) ? o0 : (w == 1) ? o1 : (w == 2) ? o2 : o3;
        dst[c * NF + r] = f2bf(src[off]);
    }
}

// ---------------------------------------------------------------------------
// Merged Q/K/V projection: blockIdx.z selects which projection.
// C[8192,512] = A[8192,512] @ W[512,512] + bias; 128x128 tile, BK=64, 4 waves.
// z==0: Q (scale 1/8, out [B,H,S,D] bf16); z==1: K ([B,H,S,D]); z==2: V (out [B,H,D,S]).
__launch_bounds__(256, 2)
__global__ void proj_qkv(const unsigned short* __restrict__ Aq,
                         const unsigned short* __restrict__ Ak,
                         const unsigned short* __restrict__ Av,
                         const unsigned short* __restrict__ WqT,
                         const unsigned short* __restrict__ WkT,
                         const unsigned short* __restrict__ WvT,
                         const float* __restrict__ bq, const float* __restrict__ bk,
                         const float* __restrict__ bv,
                         unsigned short* __restrict__ Qh, unsigned short* __restrict__ Kh,
                         unsigned short* __restrict__ VTs) {
    __shared__ unsigned short smem[2 * 128 * 64];
    unsigned short* As = smem;
    unsigned short* Bs = smem + 128 * 64;

    const int mode = blockIdx.z;
    const unsigned short* A  = (mode == 0) ? Aq : (mode == 1) ? Ak : Av;
    const unsigned short* WT = (mode == 0) ? WqT : (mode == 1) ? WkT : WvT;
    const float* bias        = (mode == 0) ? bq : (mode == 1) ? bk : bv;

    const int t = threadIdx.x;
    const int wid = t >> 6;
    const int lane = t & 63;
    const int l15 = lane & 15;
    const int lhi = lane >> 4;
    const int m0 = blockIdx.x * 128;
    const int n0 = blockIdx.y * 128;
    const int wm = (wid >> 1) * 64;
    const int wn = (wid & 1) * 64;

    const int srow = t >> 3;
    const int scol = ((t & 7) * 16) ^ ((srow & 7) << 4);

    const f32x4 zero4 = {0.f, 0.f, 0.f, 0.f};
    f32x4 acc[4][4];
#pragma unroll
    for (int i = 0; i < 4; ++i)
#pragma unroll
        for (int j = 0; j < 4; ++j) acc[i][j] = zero4;

    for (int k0 = 0; k0 < NF; k0 += 64) {
        __syncthreads();
#pragma unroll
        for (int i = 0; i < 4; ++i) {
            const char* sa = (const char*)A + ((size_t)(m0 + i * 32 + srow) * NF + k0) * 2 + scol;
            load_lds16(sa, (char*)As + i * 4096 + wid * 1024);
            const char* sb = (const char*)WT + ((size_t)(n0 + i * 32 + srow) * NF + k0) * 2 + scol;
            load_lds16(sb, (char*)Bs + i * 4096 + wid * 1024);
        }
        asm volatile("s_waitcnt vmcnt(0)" ::: "memory");
        __syncthreads();

#pragma unroll
        for (int ks = 0; ks < 2; ++ks) {
            bf16x8 af[4], bfr[4];
#pragma unroll
            for (int i = 0; i < 4; ++i) {
                int ra = wm + i * 16 + l15;
                int ca = (ks * 64 + lhi * 16) ^ ((ra & 7) << 4);
                af[i] = *(const bf16x8*)((const char*)As + ra * 128 + ca);
                int rb = wn + i * 16 + l15;
                int cb = (ks * 64 + lhi * 16) ^ ((rb & 7) << 4);
                bfr[i] = *(const bf16x8*)((const char*)Bs + rb * 128 + cb);
            }
#pragma unroll
            for (int mi = 0; mi < 4; ++mi)
#pragma unroll
                for (int ni = 0; ni < 4; ++ni)
                    acc[mi][ni] = __builtin_amdgcn_mfma_f32_16x16x32_bf16(af[mi], bfr[ni], acc[mi][ni], 0, 0, 0);
        }
    }

    // epilogue: C/D layout col = lane&15, row = (lane>>4)*4 + reg
#pragma unroll
    for (int ni = 0; ni < 4; ++ni) {
        int col = n0 + wn + ni * 16 + l15;
        float bv2 = bias[col];
#pragma unroll
        for (int mi = 0; mi < 4; ++mi) {
#pragma unroll
            for (int r = 0; r < 4; ++r) {
                int row = m0 + wm + mi * 16 + lhi * 4 + r;
                float val = acc[mi][ni][r] + bv2;
                int b = row >> 12, s = row & (NS - 1);
                int hh = col >> 6, d = col & (ND - 1);
                if (mode == 0) {
                    val *= 0.125f;  // fold 1/sqrt(D)
                    Qh[((size_t)(b * NH + hh) * NS + s) * ND + d] = f2bf(val);
                } else if (mode == 1) {
                    Kh[((size_t)(b * NH + hh) * NS + s) * ND + d] = f2bf(val);
                } else {  // V transposed: [B,H,D,S]
                    VTs[((size_t)(b * NH + hh) * ND + d) * NS + s] = f2bf(val);
                }
            }
        }
    }
}

// Output projection: fp32 out, row-major [8192,512].
__launch_bounds__(256, 2)
__global__ void proj_o(const unsigned short* __restrict__ A,
                       const unsigned short* __restrict__ WT,
                       const float* __restrict__ bias,
                       float* __restrict__ Out) {
    __shared__ unsigned short smem[2 * 128 * 64];
    unsigned short* As = smem;
    unsigned short* Bs = smem + 128 * 64;

    const int t = threadIdx.x;
    const int wid = t >> 6;
    const int lane = t & 63;
    const int l15 = lane & 15;
    const int lhi = lane >> 4;
    const int m0 = blockIdx.x * 128;
    const int n0 = blockIdx.y * 128;
    const int wm = (wid >> 1) * 64;
    const int wn = (wid & 1) * 64;

    const int srow = t >> 3;
    const int scol = ((t & 7) * 16) ^ ((srow & 7) << 4);

    const f32x4 zero4 = {0.f, 0.f, 0.f, 0.f};
    f32x4 acc[4][4];
#pragma unroll
    for (int i = 0; i < 4; ++i)
#pragma unroll
        for (int j = 0; j < 4; ++j) acc[i][j] = zero4;

    for (int k0 = 0; k0 < NF; k0 += 64) {
        __syncthreads();
#pragma unroll
        for (int i = 0; i < 4; ++i) {
            const char* sa = (const char*)A + ((size_t)(m0 + i * 32 + srow) * NF + k0) * 2 + scol;
            load_lds16(sa, (char*)As + i * 4096 + wid * 1024);
            const char* sb = (const char*)WT + ((size_t)(n0 + i * 32 + srow) * NF + k0) * 2 + scol;
            load_lds16(sb, (char*)Bs + i * 4096 + wid * 1024);
        }
        asm volatile("s_waitcnt vmcnt(0)" ::: "memory");
        __syncthreads();

#pragma unroll
        for (int ks = 0; ks < 2; ++ks) {
            bf16x8 af[4], bfr[4];
#pragma unroll
            for (int i = 0; i < 4; ++i) {
                int ra = wm + i * 16 + l15;
                int ca = (ks * 64 + lhi * 16) ^ ((ra & 7) << 4);
                af[i] = *(const bf16x8*)((const char*)As + ra * 128 + ca);
                int rb = wn + i * 16 + l15;
                int cb = (ks * 64 + lhi * 16) ^ ((rb & 7) << 4);
                bfr[i] = *(const bf16x8*)((const char*)Bs + rb * 128 + cb);
            }
#pragma unroll
            for (int mi = 0; mi < 4; ++mi)
#pragma unroll
                for (int ni = 0; ni < 4; ++ni)
                    acc[mi][ni] = __builtin_amdgcn_mfma_f32_16x16x32_bf16(af[mi], bfr[ni], acc[mi][ni], 0, 0, 0);
        }
    }

#pragma unroll
    for (int ni = 0; ni < 4; ++ni) {
        int col = n0 + wn + ni * 16 + l15;
        float bv2 = bias[col];
#pragma unroll
        for (int mi = 0; mi < 4; ++mi)
#pragma unroll
            for (int r = 0; r < 4; ++r) {
                int row = m0 + wm + mi * 16 + lhi * 4 + r;
                Out[(size_t)row * NF + col] = acc[mi][ni][r] + bv2;
            }
    }
}

// ---------------------------------------------------------------------------
// Fused causal flash attention, swapped-QK^T 32x32 MFMA structure.
// Block = 2 waves, each wave owns 32 Q rows (Q-tile 64). KV tile 64, double-buffered.
// S^T = mfma(A=K, B=Q): D col = q = lane&31 (each lane owns ONE q row);
//   D row = kv = (r&3) + 8*(r>>2) + 4*(lane>>5) + 32*frag  [m74-verified layout].
// Softmax: lane-local ops + shfl_xor(32) (partner lane holds the other 32 kv).
// P stays in registers: pack bf16 pairs, half-swap exchange -> PV B-fragments.
// O^T = mfma(A=V^T, B=P^T): V pre-transposed in HBM ([B,H,D,S]) -> plain b128 LDS reads.
__launch_bounds__(128, 2)
__global__ void attn_fused(const unsigned short* __restrict__ Qh,
                           const unsigned short* __restrict__ Kh,
                           const unsigned short* __restrict__ VT,
                           unsigned short* __restrict__ Cc) {
    __shared__ unsigned short smem[16384];  // 32KB: 2 x (K 8KB | V 8KB)

    const int t = threadIdx.x;
    const int wid = t >> 6;       // 0..1
    const int lane = t & 63;
    const int l31 = lane & 31;
    const int h = lane >> 5;
    const int qt = 63 - (int)blockIdx.x;  // heavy tiles dispatch first
    const int hh = blockIdx.y, b = blockIdx.z;
    const int q0 = qt * 64;
    const size_t bh = (size_t)b * NH + hh;
    const char* Qp = (const char*)(Qh + bh * NS * ND);
    const char* Kp = (const char*)(Kh + bh * NS * ND);
    const char* Vp = (const char*)(VT + bh * (size_t)ND * NS);

    // Q fragments (B operand): Q[q=l31][16*kc + 8*h + j], contiguous 16B
    const int qrow = q0 + wid * 32 + l31;
    bf16x8 qf[4];
#pragma unroll
    for (int kc = 0; kc < 4; ++kc)
        qf[kc] = *(const bf16x8*)(Qp + (size_t)qrow * 128 + kc * 32 + h * 16);

    f32x16 o[2];
#pragma unroll
    for (int r = 0; r < 16; ++r) { o[0][r] = 0.f; o[1][r] = 0.f; }
    float m_run = -1e30f, l_run = 0.f;

    // staging: wave0 loads K tile, wave1 loads V^T tile (8 x 1KB each)
    const int srow = lane >> 3;
    const int scol = ((lane & 7) * 16) ^ ((srow & 7) << 4);
    const size_t koff = (size_t)srow * 128 + scol;
    const size_t voff = (size_t)srow * (NS * 2) + scol;

    auto STAGE = [&](int buf, int kv0) {
        char* lk = (char*)smem + buf * 16384;
        if (wid == 0) {
            const char* g = Kp + (size_t)kv0 * 128 + koff;
#pragma unroll
            for (int i = 0; i < 8; ++i)
                load_lds16(g + i * 1024, lk + i * 1024);
        } else {
            const char* g = Vp + (size_t)kv0 * 2 + voff;
            char* lv = lk + 8192;
#pragma unroll
            for (int i = 0; i < 8; ++i)
                load_lds16(g + (size_t)i * 8 * (NS * 2), lv + i * 1024);
        }
    };

    const int nkv = qt + 1;
    const int sw = (l31 & 7) << 4;
    STAGE(0, 0);
    int cur = 0;

    for (int kt = 0; kt < nkv; ++kt) {
        if (kt + 1 < nkv) {
            STAGE(cur ^ 1, (kt + 1) * 64);
            asm volatile("s_waitcnt vmcnt(8)" ::: "memory");  // drain current tile only
        } else {
            asm volatile("s_waitcnt vmcnt(0)" ::: "memory");
        }
        __builtin_amdgcn_s_barrier();
        __builtin_amdgcn_sched_barrier(0);

        const char* Kb = (const char*)smem + cur * 16384;
        const char* Vb = Kb + 8192;

        // S^T = K @ Q^T
        f32x16 sT[2];
#pragma unroll
        for (int r = 0; r < 16; ++r) { sT[0][r] = 0.f; sT[1][r] = 0.f; }
#pragma unroll
        for (int kvi = 0; kvi < 2; ++kvi) {
            const int row = kvi * 32 + l31;
#pragma unroll
            for (int kc = 0; kc < 4; ++kc) {
                bf16x8 kf = *(const bf16x8*)(Kb + row * 128 + ((kc * 32 + h * 16) ^ sw));
                sT[kvi] = __builtin_amdgcn_mfma_f32_32x32x16_bf16(kf, qf[kc], sT[kvi], 0, 0, 0);
            }
        }

        // causal mask (only the diagonal tile)
        if (kt == qt) {
#pragma unroll
            for (int kvi = 0; kvi < 2; ++kvi)
#pragma unroll
                for (int r = 0; r < 16; ++r) {
                    int kv = kt * 64 + kvi * 32 + (r & 3) + ((r >> 2) << 3) + h * 4;
                    if (kv > qrow) sT[kvi][r] = -1e30f;
                }
        }

        // online softmax: lane owns one q; partner lane (xor 32) holds other 32 kv
        float pm = -1e30f;
#pragma unroll
        for (int kvi = 0; kvi < 2; ++kvi)
#pragma unroll
            for (int r = 0; r < 16; ++r) pm = fmaxf(pm, sT[kvi][r]);
        pm = fmaxf(pm, __shfl_xor(pm, 32));

        if (__ballot(pm > m_run + 8.0f) != 0ull) {  // defer-max (T13)
            float mnew = fmaxf(m_run, pm);
            float a = __expf(m_run - mnew);
            m_run = mnew;
            l_run *= a;
#pragma unroll
            for (int di = 0; di < 2; ++di)
#pragma unroll
                for (int r = 0; r < 16; ++r) o[di][r] *= a;
        }
        float rs = 0.f;
#pragma unroll
        for (int kvi = 0; kvi < 2; ++kvi)
#pragma unroll
            for (int r = 0; r < 16; ++r) {
                float p = __expf(sT[kvi][r] - m_run);
                sT[kvi][r] = p;
                rs += p;
            }
        rs += __shfl_xor(rs, 32);
        l_run += rs;

        // pack P to bf16 pair-words; word w[kvi][i] covers kv pair base
        // kvi*32 + 2*(i&1) + 8*(i>>1) + 4*h  (holds kv {base, base+1})
        unsigned int w[2][8];
#pragma unroll
        for (int kvi = 0; kvi < 2; ++kvi)
#pragma unroll
            for (int i = 0; i < 8; ++i)
                w[kvi][i] = (unsigned int)f2bf(sT[kvi][2 * i]) |
                            ((unsigned int)f2bf(sT[kvi][2 * i + 1]) << 16);

        // exchange halves -> B-operand fragments pf[ck]: element j = P[q=own][kv=16ck+8h+j]
        // h=0 lane needs partner's (h=1) words {pb+0,pb+1} (their kv 4..7 block);
        // h=1 lane needs partner's (h=0) words {pb+2,pb+3} (their kv 8..11 block).
        // Each side therefore CONTRIBUTES the word the other side needs (value-select, not
        // index-select, to avoid runtime-indexed register arrays).
        union FB { unsigned int u[4]; bf16x8 v; };
        bf16x8 pf[4];
#pragma unroll
        for (int ck = 0; ck < 4; ++ck) {
            const int kvi = ck >> 1, pb = (ck & 1) * 4;
            unsigned int aSrc = h ? w[kvi][pb + 0] : w[kvi][pb + 2];
            unsigned int bSrc = h ? w[kvi][pb + 1] : w[kvi][pb + 3];
            unsigned int sA = (unsigned int)__shfl_xor((int)aSrc, 32);
            unsigned int sB = (unsigned int)__shfl_xor((int)bSrc, 32);
            FB f;
            f.u[0] = (h == 0) ? w[kvi][pb + 0] : sA;
            f.u[1] = (h == 0) ? w[kvi][pb + 1] : sB;
            f.u[2] = (h == 0) ? sA : w[kvi][pb + 2];
            f.u[3] = (h == 0) ? sB : w[kvi][pb + 3];
            pf[ck] = f.v;
        }

        // O^T += V^T @ P^T
#pragma unroll
        for (int di = 0; di < 2; ++di) {
            const int row = di * 32 + l31;
#pragma unroll
            for (int ck = 0; ck < 4; ++ck) {
                bf16x8 vf = *(const bf16x8*)(Vb + row * 128 + ((ck * 32 + h * 16) ^ sw));
                o[di] = __builtin_amdgcn_mfma_f32_32x32x16_bf16(vf, pf[ck], o[di], 0, 0, 0);
            }
        }

        __builtin_amdgcn_sched_barrier(0);
        __builtin_amdgcn_s_barrier();  // all reads of buf[cur] done before next overwrite
        cur ^= 1;
    }

    // normalize + store: lane owns row q; d = 32*di + 8*tq + 4*h + (0..3) consecutive
    float inv = 1.0f / l_run;
    size_t obase = ((size_t)b * NS + qrow) * NF + hh * ND;
#pragma unroll
    for (int di = 0; di < 2; ++di)
#pragma unroll
        for (int tq = 0; tq < 4; ++tq) {
            ushort4 pk;
            pk.x = f2bf(o[di][4 * tq + 0] * inv);
            pk.y = f2bf(o[di][4 * tq + 1] * inv);
            pk.z = f2bf(o[di][4 * tq + 2] * inv);
            pk.w = f2bf(o[di][4 * tq + 3] * inv);
            *(ushort4*)(Cc + obase + di * 32 + tq * 8 + h * 4) = pk;
        }
}

// ---------------------------------------------------------------------------
extern "C" void kernel_launch(void* const* d_in, const int* in_sizes, int n_in,
                              void* d_out, int out_size, void* d_ws, size_t ws_size,
                              hipStream_t stream) {
    const float* q = (const float*)d_in[0];
    const float* k = (const float*)d_in[1];
    const float* v = (const float*)d_in[2];
    // d_in[3] = mask (deterministic causal; applied analytically)
    const float* wq = (const float*)d_in[4];
    const float* bq = (const float*)d_in[5];
    const float* wk = (const float*)d_in[6];
    const float* bk = (const float*)d_in[7];
    const float* wv = (const float*)d_in[8];
    const float* bv = (const float*)d_in[9];
    const float* wo = (const float*)d_in[10];
    const float* bo = (const float*)d_in[11];

    const size_t MB = 1u << 20;
    char* ws = (char*)d_ws;
    unsigned short* qb  = (unsigned short*)(ws);             // 8MB (reused as concat)
    unsigned short* kb  = (unsigned short*)(ws + 8 * MB);    // 8MB
    unsigned short* vb  = (unsigned short*)(ws + 16 * MB);   // 8MB
    unsigned short* wqT = (unsigned short*)(ws + 24 * MB);
    unsigned short* wkT = (unsigned short*)(ws + 24 * MB + 512 * 1024);
    unsigned short* wvT = (unsigned short*)(ws + 25 * MB);
    unsigned short* woT = (unsigned short*)(ws + 25 * MB + 512 * 1024);
    unsigned short* Qh  = (unsigned short*)(ws + 26 * MB);   // 8MB [B,H,S,D] pre-scaled
    unsigned short* Kh  = (unsigned short*)(ws + 34 * MB);   // 8MB [B,H,S,D]
    unsigned short* VTs = (unsigned short*)(ws + 42 * MB);   // 8MB [B,H,D,S]

    convert_all<<<dim3(2048), dim3(256), 0, stream>>>(q, k, v, qb, kb, vb,
                                                      wq, wk, wv, wo, wqT, wkT, wvT, woT);

    proj_qkv<<<dim3(NM / 128, NF / 128, 3), dim3(256), 0, stream>>>(
        qb, kb, vb, wqT, wkT, wvT, bq, bk, bv, Qh, Kh, VTs);

    attn_fused<<<dim3(64, NH, NB), dim3(128), 0, stream>>>(Qh, Kh, VTs, qb /*concat*/);

    proj_o<<<dim3(NM / 128, NF / 128), dim3(256), 0, stream>>>(qb, woT, bo, (float*)d_out);
}